// Round 2
// baseline (693.292 us; speedup 1.0000x reference)
//
#include <hip/hip_runtime.h>
#include <math.h>

// SNN forward, fused. Inputs f32, output f32 [2048][200].
// R20 = R18 (fp8 weights + 256-entry LDS spike-LUT, 253us/dispatch) + occupancy
// push from 4 -> 5 blocks/CU:
//  - ubits: 12 -> 8 dwords/row and 150 rows (was 160). Rows t>=150 are never
//    stored; reads clamp to row 149 (finite garbage x discarded-by-scan).
//    XOR bank-swizzle ((row&12)<<2 on byte addr) keeps b128 reads 2-way (free).
//  - zero-init pass deleted: every ubits row read is written by the previous
//    layer's scan first; xa pad columns (j=20..23) are staged as 0.
//  - LUT built AFTER layer 1 and placed over xa's then-dead bytes.
//  - LDS 37952 -> 32464 B  => 5 blocks/CU (20 waves/CU, was 16).
//  - output-loop barriers elided while softmax is a warmup no-op (13 vs 20).
// (R19's __builtin_amdgcn_writelane does not exist on this toolchain; mask
//  capture stays in the known-good lane==r/cndmask form.)

#define T_N 150
#define DIN 20
#define H 256
#define NOUT 200
#define NMT 10
#define CST 20             // sc col stride (f32): 16 rows + 4 pad
#define XAP 24             // xa row stride (bf16 shorts)

// LDS map (bytes):
#define SC_OFF  0          // 5116 f32 = 20464 B (max idx 5115)
#define UB0_OFF 20464      // 150 rows x 32 B, swizzled
#define LUT_OFF 25264      // 256 x 8 B (built post-layer-1)
#define UB1_OFF 27312      // 150 rows x 32 B
#define XA_OFF  25264      // 150 x 24 shorts = 7200 B over lut+ub1+pad (dead then)
#define SMEM_SZ 32464      // -> 32768 after 512B granule => 5 blocks/CU

// d_ws layout: [0,5120) shorts = bf16 W1; then fp8 bytes W2,W3,W4,Wo
#define N_W1 5120
#define F8_W2 0
#define F8_W3 65536
#define F8_W4 131072
#define F8_WO 196608
#define F8_TOT 247808

typedef short s16x8 __attribute__((ext_vector_type(8)));
typedef float f32x4 __attribute__((ext_vector_type(4)));
typedef unsigned int u32x4 __attribute__((ext_vector_type(4)));

__device__ __forceinline__ unsigned short f2bf(float f) {
  union { float f; unsigned int i; } v; v.f = f;
  unsigned int r = v.i + 0x7FFFu + ((v.i >> 16) & 1u);
  return (unsigned short)(r >> 16);
}

// f32 -> OCP e4m3 (RNE, handles subnormals; inputs |f| <= 0.25, no sat needed)
__device__ __forceinline__ unsigned char f2e4m3(float f) {
  union { float f; unsigned u; } v; v.f = f;
  unsigned s = (v.u >> 24) & 0x80u;
  unsigned mag = v.u & 0x7FFFFFFFu;
  if (mag == 0) return (unsigned char)s;
  int e = (int)(mag >> 23) - 127;
  unsigned man = mag & 0x7FFFFFu;
  unsigned q;
  if (e >= -6) {
    unsigned r = man + 0x7FFFFu + ((man >> 20) & 1u);
    if (r >= 0x800000u) { e += 1; r -= 0x800000u; }
    q = ((unsigned)(e + 7) << 3) | (r >> 20);
  } else {
    unsigned mant = 0x800000u | man;
    int sh = 14 - e;
    if (sh > 31) q = 0;
    else {
      unsigned fl = mant >> sh;
      unsigned rem = mant & ((1u << sh) - 1u);
      unsigned half = 1u << (sh - 1);
      q = fl + ((rem > half || (rem == half && (fl & 1))) ? 1u : 0u);
    }
  }
  return (unsigned char)(s | q);
}

__global__ void cvt_weights(const float* __restrict__ W1, const float* __restrict__ W2,
                            const float* __restrict__ W3, const float* __restrict__ W4,
                            const float* __restrict__ Wo, unsigned short* __restrict__ ws) {
  int idx = blockIdx.x * blockDim.x + threadIdx.x;
  int stride = gridDim.x * blockDim.x;
  for (int i = idx; i < N_W1; i += stride) ws[i] = f2bf(W1[i]);
  unsigned char* f8 = (unsigned char*)(ws + N_W1);
  for (int i = idx; i < F8_TOT; i += stride) {
    float v;
    if (i < F8_W3)      v = W2[i - F8_W2];
    else if (i < F8_W4) v = W3[i - F8_W3];
    else if (i < F8_WO) v = W4[i - F8_W4];
    else                v = Wo[i - F8_WO];
    f8[i] = f2e4m3(v);
  }
}

// expand 8 spike bits -> 8 fp8 e4m3 bytes (0x00 / 0x38) packed in a long
// (used only to BUILD the LDS LUT).
__device__ __forceinline__ long expand8_f8(unsigned t) {
  unsigned lo = ((t & 0xFu) * 0x204081u) & 0x01010101u;
  unsigned hi = ((t >> 4) * 0x204081u) & 0x01010101u;
  lo *= 0x38u; hi *= 0x38u;
  union { unsigned u[2]; long l; } cv; cv.u[0] = lo; cv.u[1] = hi;
  return cv.l;
}

__global__ __launch_bounds__(256, 5) void snn_fused(
    const float* __restrict__ x,             // [2048][150][20] f32
    const unsigned short* __restrict__ wsb,  // d_ws: bf16 W1 + fp8 W2..Wo
    const float* __restrict__ b1,            // [256] f32
    const float* __restrict__ b2,
    const float* __restrict__ b3,
    const float* __restrict__ b4,
    float* __restrict__ out)                 // [2048][200] f32
{
  __shared__ __align__(16) char smem[SMEM_SZ];
  float* sc = (float*)(smem + SC_OFF);
  char* const ubb0 = smem + UB0_OFF;
  char* const ubb1 = smem + UB1_OFF;
  long* lut = (long*)(smem + LUT_OFF);
  unsigned short* xa = (unsigned short*)(smem + XA_OFF);

  const int tid  = threadIdx.x;
  const int lane = tid & 63;
  const int wave = tid >> 6;    // 0..3
  const int c16  = lane & 15;
  const int quad = lane >> 4;
  const int shq  = quad * 8;
  const int shq2 = (quad == 3) ? 16 : shq;  // quad3 re-reads quad2's xa slot (its weights are 0)
  const int bidx = blockIdx.x;
  const int colw = 64 * wave;   // wave owns cols [64w, 64w+64)
  const int cb   = colw + c16;

  const unsigned char* f8 = (const unsigned char*)(wsb + N_W1);

  auto store_c = [&](f32x4* c) {
    #pragma unroll
    for (int i = 0; i < 4; ++i)
      *(f32x4*)&sc[(cb + 16 * i) * CST + quad * 4] = c[i];
  };

  // fused membrane scan, two-half form; 64 lanes own the wave's 64 cols.
  auto scan_tile = [&](int mt, float& m, char* wb) {
    const f32x4* vp = (const f32x4*)&sc[(colw + lane) * CST];
    unsigned long long keep = 0ull;
    #pragma unroll
    for (int h = 0; h < 2; ++h) {
      f32x4 v0 = vp[2 * h], v1 = vp[2 * h + 1];
      #pragma unroll
      for (int rr = 0; rr < 8; ++rr) {
        int r = 8 * h + rr;
        int t = mt * 16 + r;
        if (t < T_N) {  // block-uniform
          float inp = (rr < 4) ? v0[rr & 3] : v1[rr & 3];
          float sel = (m > 1.0f) ? (inp - 1.0f) : inp;
          m = 0.9f * m + sel;
          unsigned long long msk = __ballot(m > 1.0f);
          if (lane == r) keep = msk;
        }
      }
    }
    int row = mt * 16 + lane;
    if (lane < 16 && row < T_N)
      *(unsigned long long*)(wb + ((row * 32 + 8 * wave) ^ ((row & 12) << 2))) = keep;
  };

  // ---- init: stage x as bf16 (pad cols j=20..23 zeroed; no other init needed) ----
  {
    const float* xb = x + (size_t)bidx * (T_N * DIN);
    for (int i = tid; i < T_N * XAP; i += 256) {
      int t = i / XAP, j = i - t * XAP;
      xa[i] = (j < DIN) ? f2bf(xb[t * DIN + j]) : (unsigned short)0;
    }
  }

  // ---- layer 1 (bf16): x @ W1^T (K=20 pad 32) -> ub0; barrier-free ----
  {
    s16x8 w1f[4];
    #pragma unroll
    for (int i = 0; i < 4; ++i) {
      int n = cb + 16 * i;
      #pragma unroll
      for (int j = 0; j < 8; ++j) {
        int k = shq + j;
        w1f[i][j] = (k < DIN) ? (short)wsb[n * DIN + k] : (short)0;
      }
      asm volatile("" : "+v"(w1f[i]));
    }
    float bc[4];
    #pragma unroll
    for (int i = 0; i < 4; ++i) bc[i] = b1[cb + 16 * i];
    float m = 0.0f;
    __syncthreads();  // xa staged
    for (int mt = 0; mt < NMT; ++mt) {
      int tr = mt * 16 + c16; if (tr > T_N - 1) tr = T_N - 1;  // rows>=150 discarded by scan
      const s16x8 a1 = *(const s16x8*)&xa[tr * XAP + shq2];
      f32x4 c[4];
      #pragma unroll
      for (int i = 0; i < 4; ++i) { f32x4 z = {bc[i], bc[i], bc[i], bc[i]}; c[i] = z; }
      #pragma unroll
      for (int i = 0; i < 4; ++i)
        c[i] = __builtin_amdgcn_mfma_f32_16x16x32_bf16(a1, w1f[i], c[i], 0, 0, 0);
      if (mt > 0) scan_tile(mt - 1, m, ubb0);
      store_c(c);
    }
    scan_tile(9, m, ubb0);
  }
  __syncthreads();  // bits0 complete; all xa reads done
  lut[tid] = expand8_f8((unsigned)tid);  // lut overlays xa (dead from here)
  __syncthreads();  // lut visible

  // ---- layers 2..4 (fp8 weights): barrier-free, bits ping-pong ----
  const float* bsl[3] = {b2, b3, b4};
  const int wofs[3] = {F8_W2, F8_W3, F8_W4};
  for (int l = 0; l < 3; ++l) {
    const unsigned char* wl = f8 + wofs[l];
    char* const ubr = (l & 1) ? ubb1 : ubb0;
    char* const ubw = (l & 1) ? ubb0 : ubb1;
    __builtin_amdgcn_sched_barrier(0);
    long wf[4][8];
    #pragma unroll
    for (int i = 0; i < 4; ++i) {
      int n = cb + 16 * i;
      #pragma unroll
      for (int ks = 0; ks < 8; ++ks) {
        wf[i][ks] = *(const long*)(wl + n * H + ks * 32 + shq);
        asm volatile("" : "+v"(wf[i][ks]));
      }
    }
    __builtin_amdgcn_sched_barrier(0);
    float bc[4];
    #pragma unroll
    for (int i = 0; i < 4; ++i) bc[i] = bsl[l][cb + 16 * i];
    float m = 0.0f;
    for (int mt = 0; mt < NMT; ++mt) {
      int trow = mt * 16 + c16; if (trow > T_N - 1) trow = T_N - 1;
      const int sw = (trow & 12) << 2;
      f32x4 c[4];
      #pragma unroll
      for (int i = 0; i < 4; ++i) { f32x4 z = {bc[i], bc[i], bc[i], bc[i]}; c[i] = z; }
      #pragma unroll
      for (int h = 0; h < 2; ++h) {
        u32x4 rm = *(const u32x4*)(ubr + ((trow * 32 + 16 * h) ^ sw));
        #pragma unroll
        for (int kk = 0; kk < 4; ++kk) {
          long a = lut[(rm[kk] >> shq) & 0xFFu];   // LDS LUT expansion
          int ks = 4 * h + kk;
          #pragma unroll
          for (int i = 0; i < 4; ++i)
            c[i] = __builtin_amdgcn_mfma_f32_16x16x32_fp8_fp8(a, wf[i][ks], c[i], 0, 0, 0);
        }
      }
      if (mt > 0) scan_tile(mt - 1, m, ubw);
      store_c(c);
    }
    scan_tile(9, m, ubw);
    __syncthreads();  // bits[ubw] complete
  }

  // ---- output layer (fp8, reads ub1): GEMM + mo-scan + softmax ----
  {
    __builtin_amdgcn_sched_barrier(0);
    long wo[4][8];
    #pragma unroll
    for (int i = 0; i < 4; ++i) {
      int n = cb + 16 * i;
      bool valid = (n < NOUT);
      #pragma unroll
      for (int ks = 0; ks < 8; ++ks) {
        wo[i][ks] = valid ? *(const long*)(f8 + F8_WO + n * H + ks * 32 + shq) : 0L;
        asm volatile("" : "+v"(wo[i][ks]));
      }
    }
    __builtin_amdgcn_sched_barrier(0);

    float mo = 0.0f;
    float a0 = 0.f, a1 = 0.f, a2 = 0.f, a3 = 0.f;

    auto moscan = [&](int mt) {
      if (tid < 208) {   // wave-local: thread tid scans col tid (within own wave's cols)
        f32x4* vp = (f32x4*)&sc[tid * CST];
        #pragma unroll
        for (int h = 0; h < 2; ++h) {
          f32x4 v0 = vp[2 * h], v1 = vp[2 * h + 1];
          #pragma unroll
          for (int rr = 0; rr < 8; ++rr) {
            int r = 8 * h + rr;
            int t = mt * 16 + r;
            if (t < T_N) {
              float inp = (rr < 4) ? v0[rr & 3] : v1[rr & 3];
              float reset = (mo > 1.0f) ? 1.0f : 0.0f;
              mo = 0.9f * mo + inp - reset;
              if (rr < 4) v0[rr & 3] = mo; else v1[rr & 3] = mo;
            }
          }
          vp[2 * h] = v0; vp[2 * h + 1] = v1;
        }
      }
    };
    auto softmax_t = [&](int mt) {
      #pragma unroll
      for (int rr = 0; rr < 4; ++rr) {
        int r = 4 * wave + rr;
        int t = mt * 16 + r;
        if (t > 50 && t < T_N) {        // wave-uniform
          const float* p = &sc[r];
          float v0 = p[lane * CST];
          float v1 = p[(64 + lane) * CST];
          float v2 = p[(128 + lane) * CST];
          bool has3 = (lane < 8);
          float v3 = has3 ? p[(192 + lane) * CST] : -INFINITY;
          float mx = fmaxf(fmaxf(v0, v1), fmaxf(v2, v3));
          #pragma unroll
          for (int d = 32; d >= 1; d >>= 1) mx = fmaxf(mx, __shfl_xor(mx, d));
          float e0 = __expf(v0 - mx), e1 = __expf(v1 - mx), e2 = __expf(v2 - mx);
          float e3 = has3 ? __expf(v3 - mx) : 0.0f;
          float s = e0 + e1 + e2 + e3;
          #pragma unroll
          for (int d = 32; d >= 1; d >>= 1) s += __shfl_xor(s, d);
          float inv = 1.0f / s;
          a0 += e0 * inv; a1 += e1 * inv; a2 += e2 * inv; a3 += e3 * inv;
        }
      }
    };

    for (int mt = 0; mt < NMT; ++mt) {
      int trow = mt * 16 + c16; if (trow > T_N - 1) trow = T_N - 1;
      const int sw = (trow & 12) << 2;
      f32x4 c[4];
      #pragma unroll
      for (int i = 0; i < 4; ++i) { f32x4 z = {0.f, 0.f, 0.f, 0.f}; c[i] = z; }
      #pragma unroll
      for (int h = 0; h < 2; ++h) {
        u32x4 rm = *(const u32x4*)(ubb1 + ((trow * 32 + 16 * h) ^ sw));
        #pragma unroll
        for (int kk = 0; kk < 4; ++kk) {
          long a = lut[(rm[kk] >> shq) & 0xFFu];   // LDS LUT expansion
          int ks = 4 * h + kk;
          #pragma unroll
          for (int i = 0; i < 4; ++i)
            c[i] = __builtin_amdgcn_mfma_f32_16x16x32_fp8_fp8(a, wo[i][ks], c[i], 0, 0, 0);
        }
      }
      // softmax(mt-1) only exists for mt-1 >= 3; before that all sc traffic is
      // wave-local (store_c / moscan on own cols) -> barrier elidable.
      if (mt >= 4) __syncthreads();   // prior softmax done reading sc
      store_c(c);
      moscan(mt);                     // wave-local after wave-local store
      if (mt >= 3) __syncthreads();   // membranes visible to all waves
      softmax_t(mt);
    }
    __syncthreads();

    // merge 4 per-wave accumulators via sc, store f32
    sc[wave * 260 + lane]       = a0;
    sc[wave * 260 + 64 + lane]  = a1;
    sc[wave * 260 + 128 + lane] = a2;
    if (lane < 8) sc[wave * 260 + 192 + lane] = a3;
    __syncthreads();
    if (tid < NOUT) {
      float v = sc[tid] + sc[260 + tid] + sc[520 + tid] + sc[780 + tid];
      out[(size_t)bidx * NOUT + tid] = v;
    }
  }
}

extern "C" void kernel_launch(void* const* d_in, const int* in_sizes, int n_in,
                              void* d_out, int out_size, void* d_ws, size_t ws_size,
                              hipStream_t stream) {
  (void)in_sizes; (void)n_in; (void)ws_size; (void)out_size;
  unsigned short* wsb = (unsigned short*)d_ws;
  cvt_weights<<<256, 256, 0, stream>>>(
      (const float*)d_in[1], (const float*)d_in[3], (const float*)d_in[5],
      (const float*)d_in[7], (const float*)d_in[9], wsb);
  snn_fused<<<2048, 256, 0, stream>>>(
      (const float*)d_in[0], wsb,
      (const float*)d_in[2], (const float*)d_in[4],
      (const float*)d_in[6], (const float*)d_in[8],
      (float*)d_out);
}

// Round 3
// 351.926 us; speedup vs baseline: 1.9700x; 1.9700x over previous
//
#include <hip/hip_runtime.h>
#include <math.h>

// SNN forward, fused. Inputs f32, output f32 [2048][200].
// R21 = R20 LDS restructure (32768 B block => 5 blocks/CU possible) but with
// __launch_bounds__(256, 4): R20's (256,5) capped VGPRs and spilled the
// wf/wo weight fragments to scratch (FETCH 17.5MB -> 1.02GB, 660us).
// The 2nd arg is a compiler *guarantee*, not a HW cap: at natural VGPR=64
// and LDS 32768, HW co-schedules 5 blocks/CU (5*32768 = 160 KiB exactly).
//  - ubits: 8 dwords/row x 150 rows, XOR bank-swizzle ((row&12)<<2).
//  - zero-init pass deleted; xa pad columns staged as 0.
//  - LUT built AFTER layer 1, overlaying xa's dead bytes.
//  - output-loop barriers elided during softmax warmup (13 vs 20).

#define T_N 150
#define DIN 20
#define H 256
#define NOUT 200
#define NMT 10
#define CST 20             // sc col stride (f32): 16 rows + 4 pad
#define XAP 24             // xa row stride (bf16 shorts)

// LDS map (bytes):
#define SC_OFF  0          // 5116 f32 = 20464 B (max idx 5115)
#define UB0_OFF 20464      // 150 rows x 32 B, swizzled
#define LUT_OFF 25264      // 256 x 8 B (built post-layer-1)
#define UB1_OFF 27312      // 150 rows x 32 B
#define XA_OFF  25264      // 150 x 24 shorts = 7200 B over lut+ub1+pad (dead then)
#define SMEM_SZ 32464      // -> 32768 after granule => 5 blocks/CU fit by LDS

// d_ws layout: [0,5120) shorts = bf16 W1; then fp8 bytes W2,W3,W4,Wo
#define N_W1 5120
#define F8_W2 0
#define F8_W3 65536
#define F8_W4 131072
#define F8_WO 196608
#define F8_TOT 247808

typedef short s16x8 __attribute__((ext_vector_type(8)));
typedef float f32x4 __attribute__((ext_vector_type(4)));
typedef unsigned int u32x4 __attribute__((ext_vector_type(4)));

__device__ __forceinline__ unsigned short f2bf(float f) {
  union { float f; unsigned int i; } v; v.f = f;
  unsigned int r = v.i + 0x7FFFu + ((v.i >> 16) & 1u);
  return (unsigned short)(r >> 16);
}

// f32 -> OCP e4m3 (RNE, handles subnormals; inputs |f| <= 0.25, no sat needed)
__device__ __forceinline__ unsigned char f2e4m3(float f) {
  union { float f; unsigned u; } v; v.f = f;
  unsigned s = (v.u >> 24) & 0x80u;
  unsigned mag = v.u & 0x7FFFFFFFu;
  if (mag == 0) return (unsigned char)s;
  int e = (int)(mag >> 23) - 127;
  unsigned man = mag & 0x7FFFFFu;
  unsigned q;
  if (e >= -6) {
    unsigned r = man + 0x7FFFFu + ((man >> 20) & 1u);
    if (r >= 0x800000u) { e += 1; r -= 0x800000u; }
    q = ((unsigned)(e + 7) << 3) | (r >> 20);
  } else {
    unsigned mant = 0x800000u | man;
    int sh = 14 - e;
    if (sh > 31) q = 0;
    else {
      unsigned fl = mant >> sh;
      unsigned rem = mant & ((1u << sh) - 1u);
      unsigned half = 1u << (sh - 1);
      q = fl + ((rem > half || (rem == half && (fl & 1))) ? 1u : 0u);
    }
  }
  return (unsigned char)(s | q);
}

__global__ void cvt_weights(const float* __restrict__ W1, const float* __restrict__ W2,
                            const float* __restrict__ W3, const float* __restrict__ W4,
                            const float* __restrict__ Wo, unsigned short* __restrict__ ws) {
  int idx = blockIdx.x * blockDim.x + threadIdx.x;
  int stride = gridDim.x * blockDim.x;
  for (int i = idx; i < N_W1; i += stride) ws[i] = f2bf(W1[i]);
  unsigned char* f8 = (unsigned char*)(ws + N_W1);
  for (int i = idx; i < F8_TOT; i += stride) {
    float v;
    if (i < F8_W3)      v = W2[i - F8_W2];
    else if (i < F8_W4) v = W3[i - F8_W3];
    else if (i < F8_WO) v = W4[i - F8_W4];
    else                v = Wo[i - F8_WO];
    f8[i] = f2e4m3(v);
  }
}

// expand 8 spike bits -> 8 fp8 e4m3 bytes (0x00 / 0x38) packed in a long
// (used only to BUILD the LDS LUT).
__device__ __forceinline__ long expand8_f8(unsigned t) {
  unsigned lo = ((t & 0xFu) * 0x204081u) & 0x01010101u;
  unsigned hi = ((t >> 4) * 0x204081u) & 0x01010101u;
  lo *= 0x38u; hi *= 0x38u;
  union { unsigned u[2]; long l; } cv; cv.u[0] = lo; cv.u[1] = hi;
  return cv.l;
}

__global__ __launch_bounds__(256, 4) void snn_fused(
    const float* __restrict__ x,             // [2048][150][20] f32
    const unsigned short* __restrict__ wsb,  // d_ws: bf16 W1 + fp8 W2..Wo
    const float* __restrict__ b1,            // [256] f32
    const float* __restrict__ b2,
    const float* __restrict__ b3,
    const float* __restrict__ b4,
    float* __restrict__ out)                 // [2048][200] f32
{
  __shared__ __align__(16) char smem[SMEM_SZ];
  float* sc = (float*)(smem + SC_OFF);
  char* const ubb0 = smem + UB0_OFF;
  char* const ubb1 = smem + UB1_OFF;
  long* lut = (long*)(smem + LUT_OFF);
  unsigned short* xa = (unsigned short*)(smem + XA_OFF);

  const int tid  = threadIdx.x;
  const int lane = tid & 63;
  const int wave = tid >> 6;    // 0..3
  const int c16  = lane & 15;
  const int quad = lane >> 4;
  const int shq  = quad * 8;
  const int shq2 = (quad == 3) ? 16 : shq;  // quad3 re-reads quad2's xa slot (its weights are 0)
  const int bidx = blockIdx.x;
  const int colw = 64 * wave;   // wave owns cols [64w, 64w+64)
  const int cb   = colw + c16;

  const unsigned char* f8 = (const unsigned char*)(wsb + N_W1);

  auto store_c = [&](f32x4* c) {
    #pragma unroll
    for (int i = 0; i < 4; ++i)
      *(f32x4*)&sc[(cb + 16 * i) * CST + quad * 4] = c[i];
  };

  // fused membrane scan, two-half form; 64 lanes own the wave's 64 cols.
  auto scan_tile = [&](int mt, float& m, char* wb) {
    const f32x4* vp = (const f32x4*)&sc[(colw + lane) * CST];
    unsigned long long keep = 0ull;
    #pragma unroll
    for (int h = 0; h < 2; ++h) {
      f32x4 v0 = vp[2 * h], v1 = vp[2 * h + 1];
      #pragma unroll
      for (int rr = 0; rr < 8; ++rr) {
        int r = 8 * h + rr;
        int t = mt * 16 + r;
        if (t < T_N) {  // block-uniform
          float inp = (rr < 4) ? v0[rr & 3] : v1[rr & 3];
          float sel = (m > 1.0f) ? (inp - 1.0f) : inp;
          m = 0.9f * m + sel;
          unsigned long long msk = __ballot(m > 1.0f);
          if (lane == r) keep = msk;
        }
      }
    }
    int row = mt * 16 + lane;
    if (lane < 16 && row < T_N)
      *(unsigned long long*)(wb + ((row * 32 + 8 * wave) ^ ((row & 12) << 2))) = keep;
  };

  // ---- init: stage x as bf16 (pad cols j=20..23 zeroed; no other init needed) ----
  {
    const float* xb = x + (size_t)bidx * (T_N * DIN);
    for (int i = tid; i < T_N * XAP; i += 256) {
      int t = i / XAP, j = i - t * XAP;
      xa[i] = (j < DIN) ? f2bf(xb[t * DIN + j]) : (unsigned short)0;
    }
  }

  // ---- layer 1 (bf16): x @ W1^T (K=20 pad 32) -> ub0; barrier-free ----
  {
    s16x8 w1f[4];
    #pragma unroll
    for (int i = 0; i < 4; ++i) {
      int n = cb + 16 * i;
      #pragma unroll
      for (int j = 0; j < 8; ++j) {
        int k = shq + j;
        w1f[i][j] = (k < DIN) ? (short)wsb[n * DIN + k] : (short)0;
      }
      asm volatile("" : "+v"(w1f[i]));
    }
    float bc[4];
    #pragma unroll
    for (int i = 0; i < 4; ++i) bc[i] = b1[cb + 16 * i];
    float m = 0.0f;
    __syncthreads();  // xa staged
    for (int mt = 0; mt < NMT; ++mt) {
      int tr = mt * 16 + c16; if (tr > T_N - 1) tr = T_N - 1;  // rows>=150 discarded by scan
      const s16x8 a1 = *(const s16x8*)&xa[tr * XAP + shq2];
      f32x4 c[4];
      #pragma unroll
      for (int i = 0; i < 4; ++i) { f32x4 z = {bc[i], bc[i], bc[i], bc[i]}; c[i] = z; }
      #pragma unroll
      for (int i = 0; i < 4; ++i)
        c[i] = __builtin_amdgcn_mfma_f32_16x16x32_bf16(a1, w1f[i], c[i], 0, 0, 0);
      if (mt > 0) scan_tile(mt - 1, m, ubb0);
      store_c(c);
    }
    scan_tile(9, m, ubb0);
  }
  __syncthreads();  // bits0 complete; all xa reads done
  lut[tid] = expand8_f8((unsigned)tid);  // lut overlays xa (dead from here)
  __syncthreads();  // lut visible

  // ---- layers 2..4 (fp8 weights): barrier-free, bits ping-pong ----
  const float* bsl[3] = {b2, b3, b4};
  const int wofs[3] = {F8_W2, F8_W3, F8_W4};
  for (int l = 0; l < 3; ++l) {
    const unsigned char* wl = f8 + wofs[l];
    char* const ubr = (l & 1) ? ubb1 : ubb0;
    char* const ubw = (l & 1) ? ubb0 : ubb1;
    __builtin_amdgcn_sched_barrier(0);
    long wf[4][8];
    #pragma unroll
    for (int i = 0; i < 4; ++i) {
      int n = cb + 16 * i;
      #pragma unroll
      for (int ks = 0; ks < 8; ++ks) {
        wf[i][ks] = *(const long*)(wl + n * H + ks * 32 + shq);
        asm volatile("" : "+v"(wf[i][ks]));
      }
    }
    __builtin_amdgcn_sched_barrier(0);
    float bc[4];
    #pragma unroll
    for (int i = 0; i < 4; ++i) bc[i] = bsl[l][cb + 16 * i];
    float m = 0.0f;
    for (int mt = 0; mt < NMT; ++mt) {
      int trow = mt * 16 + c16; if (trow > T_N - 1) trow = T_N - 1;
      const int sw = (trow & 12) << 2;
      f32x4 c[4];
      #pragma unroll
      for (int i = 0; i < 4; ++i) { f32x4 z = {bc[i], bc[i], bc[i], bc[i]}; c[i] = z; }
      #pragma unroll
      for (int h = 0; h < 2; ++h) {
        u32x4 rm = *(const u32x4*)(ubr + ((trow * 32 + 16 * h) ^ sw));
        #pragma unroll
        for (int kk = 0; kk < 4; ++kk) {
          long a = lut[(rm[kk] >> shq) & 0xFFu];   // LDS LUT expansion
          int ks = 4 * h + kk;
          #pragma unroll
          for (int i = 0; i < 4; ++i)
            c[i] = __builtin_amdgcn_mfma_f32_16x16x32_fp8_fp8(a, wf[i][ks], c[i], 0, 0, 0);
        }
      }
      if (mt > 0) scan_tile(mt - 1, m, ubw);
      store_c(c);
    }
    scan_tile(9, m, ubw);
    __syncthreads();  // bits[ubw] complete
  }

  // ---- output layer (fp8, reads ub1): GEMM + mo-scan + softmax ----
  {
    __builtin_amdgcn_sched_barrier(0);
    long wo[4][8];
    #pragma unroll
    for (int i = 0; i < 4; ++i) {
      int n = cb + 16 * i;
      bool valid = (n < NOUT);
      #pragma unroll
      for (int ks = 0; ks < 8; ++ks) {
        wo[i][ks] = valid ? *(const long*)(f8 + F8_WO + n * H + ks * 32 + shq) : 0L;
        asm volatile("" : "+v"(wo[i][ks]));
      }
    }
    __builtin_amdgcn_sched_barrier(0);

    float mo = 0.0f;
    float a0 = 0.f, a1 = 0.f, a2 = 0.f, a3 = 0.f;

    auto moscan = [&](int mt) {
      if (tid < 208) {   // wave-local: thread tid scans col tid
        f32x4* vp = (f32x4*)&sc[tid * CST];
        #pragma unroll
        for (int h = 0; h < 2; ++h) {
          f32x4 v0 = vp[2 * h], v1 = vp[2 * h + 1];
          #pragma unroll
          for (int rr = 0; rr < 8; ++rr) {
            int r = 8 * h + rr;
            int t = mt * 16 + r;
            if (t < T_N) {
              float inp = (rr < 4) ? v0[rr & 3] : v1[rr & 3];
              float reset = (mo > 1.0f) ? 1.0f : 0.0f;
              mo = 0.9f * mo + inp - reset;
              if (rr < 4) v0[rr & 3] = mo; else v1[rr & 3] = mo;
            }
          }
          vp[2 * h] = v0; vp[2 * h + 1] = v1;
        }
      }
    };
    auto softmax_t = [&](int mt) {
      #pragma unroll
      for (int rr = 0; rr < 4; ++rr) {
        int r = 4 * wave + rr;
        int t = mt * 16 + r;
        if (t > 50 && t < T_N) {        // wave-uniform
          const float* p = &sc[r];
          float v0 = p[lane * CST];
          float v1 = p[(64 + lane) * CST];
          float v2 = p[(128 + lane) * CST];
          bool has3 = (lane < 8);
          float v3 = has3 ? p[(192 + lane) * CST] : -INFINITY;
          float mx = fmaxf(fmaxf(v0, v1), fmaxf(v2, v3));
          #pragma unroll
          for (int d = 32; d >= 1; d >>= 1) mx = fmaxf(mx, __shfl_xor(mx, d));
          float e0 = __expf(v0 - mx), e1 = __expf(v1 - mx), e2 = __expf(v2 - mx);
          float e3 = has3 ? __expf(v3 - mx) : 0.0f;
          float s = e0 + e1 + e2 + e3;
          #pragma unroll
          for (int d = 32; d >= 1; d >>= 1) s += __shfl_xor(s, d);
          float inv = 1.0f / s;
          a0 += e0 * inv; a1 += e1 * inv; a2 += e2 * inv; a3 += e3 * inv;
        }
      }
    };

    for (int mt = 0; mt < NMT; ++mt) {
      int trow = mt * 16 + c16; if (trow > T_N - 1) trow = T_N - 1;
      const int sw = (trow & 12) << 2;
      f32x4 c[4];
      #pragma unroll
      for (int i = 0; i < 4; ++i) { f32x4 z = {0.f, 0.f, 0.f, 0.f}; c[i] = z; }
      #pragma unroll
      for (int h = 0; h < 2; ++h) {
        u32x4 rm = *(const u32x4*)(ubb1 + ((trow * 32 + 16 * h) ^ sw));
        #pragma unroll
        for (int kk = 0; kk < 4; ++kk) {
          long a = lut[(rm[kk] >> shq) & 0xFFu];   // LDS LUT expansion
          int ks = 4 * h + kk;
          #pragma unroll
          for (int i = 0; i < 4; ++i)
            c[i] = __builtin_amdgcn_mfma_f32_16x16x32_fp8_fp8(a, wo[i][ks], c[i], 0, 0, 0);
        }
      }
      // softmax(mt-1) only exists for mt-1 >= 3; before that all sc traffic is
      // wave-local (store_c / moscan on own cols) -> barrier elidable.
      if (mt >= 4) __syncthreads();   // prior softmax done reading sc
      store_c(c);
      moscan(mt);                     // wave-local after wave-local store
      if (mt >= 3) __syncthreads();   // membranes visible to all waves
      softmax_t(mt);
    }
    __syncthreads();

    // merge 4 per-wave accumulators via sc, store f32
    sc[wave * 260 + lane]       = a0;
    sc[wave * 260 + 64 + lane]  = a1;
    sc[wave * 260 + 128 + lane] = a2;
    if (lane < 8) sc[wave * 260 + 192 + lane] = a3;
    __syncthreads();
    if (tid < NOUT) {
      float v = sc[tid] + sc[260 + tid] + sc[520 + tid] + sc[780 + tid];
      out[(size_t)bidx * NOUT + tid] = v;
    }
  }
}

extern "C" void kernel_launch(void* const* d_in, const int* in_sizes, int n_in,
                              void* d_out, int out_size, void* d_ws, size_t ws_size,
                              hipStream_t stream) {
  (void)in_sizes; (void)n_in; (void)ws_size; (void)out_size;
  unsigned short* wsb = (unsigned short*)d_ws;
  cvt_weights<<<256, 256, 0, stream>>>(
      (const float*)d_in[1], (const float*)d_in[3], (const float*)d_in[5],
      (const float*)d_in[7], (const float*)d_in[9], wsb);
  snn_fused<<<2048, 256, 0, stream>>>(
      (const float*)d_in[0], wsb,
      (const float*)d_in[2], (const float*)d_in[4],
      (const float*)d_in[6], (const float*)d_in[8],
      (float*)d_out);
}

// Round 4
// 348.887 us; speedup vs baseline: 1.9872x; 1.0087x over previous
//
#include <hip/hip_runtime.h>
#include <math.h>

// SNN forward, fused. Inputs f32, output f32 [2048][200].
// R22: R21's char-blob LDS caused ~135 MB/dispatch scratch spill (compiler
// couldn't disambiguate sc/lut/ubits through reinterpret casts -> live-range
// blowup). Restore R18-style DISTINCT typed __shared__ arrays, and drop the
// xa staging buffer entirely: layer-1 A-fragments load straight from global x
// (block slice = 12 KB, L1/L2-resident) with inline f2bf.
// LDS = sc 20464 + ub0 4800 + ub1 4800 + lut 2048 = 32112 B -> 32768 granule
// => 5 blocks/CU. launch_bounds stays (256,4) (no VGPR cap).
//  - ubits: 8 dwords/row x 150 rows, XOR bank-swizzle ((row&12)<<2).
//  - LUT built at kernel start; visibility covered by post-layer-1 barrier.
//  - output-loop barriers elided during softmax warmup (13 vs 20).

#define T_N 150
#define DIN 20
#define H 256
#define NOUT 200
#define NMT 10
#define CST 20             // sc col stride (f32): 16 rows + 4 pad

// d_ws layout: [0,5120) shorts = bf16 W1; then fp8 bytes W2,W3,W4,Wo
#define N_W1 5120
#define F8_W2 0
#define F8_W3 65536
#define F8_W4 131072
#define F8_WO 196608
#define F8_TOT 247808

typedef short s16x8 __attribute__((ext_vector_type(8)));
typedef float f32x4 __attribute__((ext_vector_type(4)));
typedef unsigned int u32x4 __attribute__((ext_vector_type(4)));

__device__ __forceinline__ unsigned short f2bf(float f) {
  union { float f; unsigned int i; } v; v.f = f;
  unsigned int r = v.i + 0x7FFFu + ((v.i >> 16) & 1u);
  return (unsigned short)(r >> 16);
}

// f32 -> OCP e4m3 (RNE, handles subnormals; inputs |f| <= 0.25, no sat needed)
__device__ __forceinline__ unsigned char f2e4m3(float f) {
  union { float f; unsigned u; } v; v.f = f;
  unsigned s = (v.u >> 24) & 0x80u;
  unsigned mag = v.u & 0x7FFFFFFFu;
  if (mag == 0) return (unsigned char)s;
  int e = (int)(mag >> 23) - 127;
  unsigned man = mag & 0x7FFFFFu;
  unsigned q;
  if (e >= -6) {
    unsigned r = man + 0x7FFFFu + ((man >> 20) & 1u);
    if (r >= 0x800000u) { e += 1; r -= 0x800000u; }
    q = ((unsigned)(e + 7) << 3) | (r >> 20);
  } else {
    unsigned mant = 0x800000u | man;
    int sh = 14 - e;
    if (sh > 31) q = 0;
    else {
      unsigned fl = mant >> sh;
      unsigned rem = mant & ((1u << sh) - 1u);
      unsigned half = 1u << (sh - 1);
      q = fl + ((rem > half || (rem == half && (fl & 1))) ? 1u : 0u);
    }
  }
  return (unsigned char)(s | q);
}

__global__ void cvt_weights(const float* __restrict__ W1, const float* __restrict__ W2,
                            const float* __restrict__ W3, const float* __restrict__ W4,
                            const float* __restrict__ Wo, unsigned short* __restrict__ ws) {
  int idx = blockIdx.x * blockDim.x + threadIdx.x;
  int stride = gridDim.x * blockDim.x;
  for (int i = idx; i < N_W1; i += stride) ws[i] = f2bf(W1[i]);
  unsigned char* f8 = (unsigned char*)(ws + N_W1);
  for (int i = idx; i < F8_TOT; i += stride) {
    float v;
    if (i < F8_W3)      v = W2[i - F8_W2];
    else if (i < F8_W4) v = W3[i - F8_W3];
    else if (i < F8_WO) v = W4[i - F8_W4];
    else                v = Wo[i - F8_WO];
    f8[i] = f2e4m3(v);
  }
}

// expand 8 spike bits -> 8 fp8 e4m3 bytes (0x00 / 0x38) packed in a long
// (used only to BUILD the LDS LUT).
__device__ __forceinline__ long expand8_f8(unsigned t) {
  unsigned lo = ((t & 0xFu) * 0x204081u) & 0x01010101u;
  unsigned hi = ((t >> 4) * 0x204081u) & 0x01010101u;
  lo *= 0x38u; hi *= 0x38u;
  union { unsigned u[2]; long l; } cv; cv.u[0] = lo; cv.u[1] = hi;
  return cv.l;
}

__global__ __launch_bounds__(256, 4) void snn_fused(
    const float* __restrict__ x,             // [2048][150][20] f32
    const unsigned short* __restrict__ wsb,  // d_ws: bf16 W1 + fp8 W2..Wo
    const float* __restrict__ b1,            // [256] f32
    const float* __restrict__ b2,
    const float* __restrict__ b3,
    const float* __restrict__ b4,
    float* __restrict__ out)                 // [2048][200] f32
{
  __shared__ float sc[5116];               // 20464 B: col-major C scratch
  __shared__ unsigned int ub0[1200];       //  4800 B: spike bits, swizzled
  __shared__ unsigned int ub1[1200];       //  4800 B
  __shared__ long lut[256];                //  2048 B: byte -> 8 fp8 spikes
                                           // total 32112 B -> 5 blocks/CU

  const int tid  = threadIdx.x;
  const int lane = tid & 63;
  const int wave = tid >> 6;    // 0..3
  const int c16  = lane & 15;
  const int quad = lane >> 4;
  const int shq  = quad * 8;
  const int shq2 = (quad == 3) ? 16 : shq;  // quad3 re-reads quad2's slice (its weights are 0)
  const int bidx = blockIdx.x;
  const int colw = 64 * wave;   // wave owns cols [64w, 64w+64)
  const int cb   = colw + c16;

  const unsigned char* f8 = (const unsigned char*)(wsb + N_W1);

  auto store_c = [&](f32x4* c) {
    #pragma unroll
    for (int i = 0; i < 4; ++i)
      *(f32x4*)&sc[(cb + 16 * i) * CST + quad * 4] = c[i];
  };

  // fused membrane scan, two-half form; 64 lanes own the wave's 64 cols.
  auto scan_tile = [&](int mt, float& m, unsigned int* wb) {
    const f32x4* vp = (const f32x4*)&sc[(colw + lane) * CST];
    unsigned long long keep = 0ull;
    #pragma unroll
    for (int h = 0; h < 2; ++h) {
      f32x4 v0 = vp[2 * h], v1 = vp[2 * h + 1];
      #pragma unroll
      for (int rr = 0; rr < 8; ++rr) {
        int r = 8 * h + rr;
        int t = mt * 16 + r;
        if (t < T_N) {  // block-uniform
          float inp = (rr < 4) ? v0[rr & 3] : v1[rr & 3];
          float sel = (m > 1.0f) ? (inp - 1.0f) : inp;
          m = 0.9f * m + sel;
          unsigned long long msk = __ballot(m > 1.0f);
          if (lane == r) keep = msk;
        }
      }
    }
    int row = mt * 16 + lane;
    if (lane < 16 && row < T_N)
      *(unsigned long long*)((char*)wb + ((row * 32 + 8 * wave) ^ ((row & 12) << 2))) = keep;
  };

  lut[tid] = expand8_f8((unsigned)tid);  // visible after post-layer-1 barrier

  // ---- layer 1 (bf16): x @ W1^T (K=20 pad 32) -> ub0; barrier-free ----
  // A-fragments straight from global x (block slice 12 KB, L1/L2-resident).
  {
    s16x8 w1f[4];
    #pragma unroll
    for (int i = 0; i < 4; ++i) {
      int n = cb + 16 * i;
      #pragma unroll
      for (int j = 0; j < 8; ++j) {
        int k = shq + j;
        w1f[i][j] = (k < DIN) ? (short)wsb[n * DIN + k] : (short)0;
      }
      asm volatile("" : "+v"(w1f[i]));
    }
    float bc[4];
    #pragma unroll
    for (int i = 0; i < 4; ++i) bc[i] = b1[cb + 16 * i];
    const float* xrow = x + (size_t)bidx * (T_N * DIN);
    float m = 0.0f;
    for (int mt = 0; mt < NMT; ++mt) {
      int tr = mt * 16 + c16; if (tr > T_N - 1) tr = T_N - 1;  // rows>=150 discarded by scan
      const float* p = xrow + tr * DIN + shq2;   // 16B-aligned (80B rows, shq2 in {0,8,16})
      f32x4 v0 = *(const f32x4*)p;
      f32x4 v1 = {0.f, 0.f, 0.f, 0.f};
      if (shq2 < 16) v1 = *(const f32x4*)(p + 4);  // quads 0,1 only (k<16)
      s16x8 a1;
      #pragma unroll
      for (int j = 0; j < 4; ++j) {
        a1[j]     = (short)f2bf(v0[j]);
        a1[4 + j] = (short)f2bf(v1[j]);   // k=20..23 -> 0 (weights there are 0)
      }
      f32x4 c[4];
      #pragma unroll
      for (int i = 0; i < 4; ++i) { f32x4 z = {bc[i], bc[i], bc[i], bc[i]}; c[i] = z; }
      #pragma unroll
      for (int i = 0; i < 4; ++i)
        c[i] = __builtin_amdgcn_mfma_f32_16x16x32_bf16(a1, w1f[i], c[i], 0, 0, 0);
      if (mt > 0) scan_tile(mt - 1, m, ub0);
      store_c(c);
    }
    scan_tile(9, m, ub0);
  }
  __syncthreads();  // bits0 complete; lut visible

  // ---- layers 2..4 (fp8 weights): barrier-free, bits ping-pong ----
  const float* bsl[3] = {b2, b3, b4};
  const int wofs[3] = {F8_W2, F8_W3, F8_W4};
  for (int l = 0; l < 3; ++l) {
    const unsigned char* wl = f8 + wofs[l];
    unsigned int* const ubr = (l & 1) ? ub1 : ub0;
    unsigned int* const ubw = (l & 1) ? ub0 : ub1;
    __builtin_amdgcn_sched_barrier(0);
    long wf[4][8];
    #pragma unroll
    for (int i = 0; i < 4; ++i) {
      int n = cb + 16 * i;
      #pragma unroll
      for (int ks = 0; ks < 8; ++ks) {
        wf[i][ks] = *(const long*)(wl + n * H + ks * 32 + shq);
        asm volatile("" : "+v"(wf[i][ks]));
      }
    }
    __builtin_amdgcn_sched_barrier(0);
    float bc[4];
    #pragma unroll
    for (int i = 0; i < 4; ++i) bc[i] = bsl[l][cb + 16 * i];
    float m = 0.0f;
    for (int mt = 0; mt < NMT; ++mt) {
      int trow = mt * 16 + c16; if (trow > T_N - 1) trow = T_N - 1;
      const int sw = (trow & 12) << 2;
      f32x4 c[4];
      #pragma unroll
      for (int i = 0; i < 4; ++i) { f32x4 z = {bc[i], bc[i], bc[i], bc[i]}; c[i] = z; }
      #pragma unroll
      for (int h = 0; h < 2; ++h) {
        u32x4 rm = *(const u32x4*)((const char*)ubr + ((trow * 32 + 16 * h) ^ sw));
        #pragma unroll
        for (int kk = 0; kk < 4; ++kk) {
          long a = lut[(rm[kk] >> shq) & 0xFFu];   // LDS LUT expansion
          int ks = 4 * h + kk;
          #pragma unroll
          for (int i = 0; i < 4; ++i)
            c[i] = __builtin_amdgcn_mfma_f32_16x16x32_fp8_fp8(a, wf[i][ks], c[i], 0, 0, 0);
        }
      }
      if (mt > 0) scan_tile(mt - 1, m, ubw);
      store_c(c);
    }
    scan_tile(9, m, ubw);
    __syncthreads();  // bits[ubw] complete
  }

  // ---- output layer (fp8, reads ub1): GEMM + mo-scan + softmax ----
  {
    __builtin_amdgcn_sched_barrier(0);
    long wo[4][8];
    #pragma unroll
    for (int i = 0; i < 4; ++i) {
      int n = cb + 16 * i;
      bool valid = (n < NOUT);
      #pragma unroll
      for (int ks = 0; ks < 8; ++ks) {
        wo[i][ks] = valid ? *(const long*)(f8 + F8_WO + n * H + ks * 32 + shq) : 0L;
        asm volatile("" : "+v"(wo[i][ks]));
      }
    }
    __builtin_amdgcn_sched_barrier(0);

    float mo = 0.0f;
    float a0 = 0.f, a1 = 0.f, a2 = 0.f, a3 = 0.f;

    auto moscan = [&](int mt) {
      if (tid < 208) {   // wave-local: thread tid scans col tid
        f32x4* vp = (f32x4*)&sc[tid * CST];
        #pragma unroll
        for (int h = 0; h < 2; ++h) {
          f32x4 v0 = vp[2 * h], v1 = vp[2 * h + 1];
          #pragma unroll
          for (int rr = 0; rr < 8; ++rr) {
            int r = 8 * h + rr;
            int t = mt * 16 + r;
            if (t < T_N) {
              float inp = (rr < 4) ? v0[rr & 3] : v1[rr & 3];
              float reset = (mo > 1.0f) ? 1.0f : 0.0f;
              mo = 0.9f * mo + inp - reset;
              if (rr < 4) v0[rr & 3] = mo; else v1[rr & 3] = mo;
            }
          }
          vp[2 * h] = v0; vp[2 * h + 1] = v1;
        }
      }
    };
    auto softmax_t = [&](int mt) {
      #pragma unroll
      for (int rr = 0; rr < 4; ++rr) {
        int r = 4 * wave + rr;
        int t = mt * 16 + r;
        if (t > 50 && t < T_N) {        // wave-uniform
          const float* p = &sc[r];
          float v0 = p[lane * CST];
          float v1 = p[(64 + lane) * CST];
          float v2 = p[(128 + lane) * CST];
          bool has3 = (lane < 8);
          float v3 = has3 ? p[(192 + lane) * CST] : -INFINITY;
          float mx = fmaxf(fmaxf(v0, v1), fmaxf(v2, v3));
          #pragma unroll
          for (int d = 32; d >= 1; d >>= 1) mx = fmaxf(mx, __shfl_xor(mx, d));
          float e0 = __expf(v0 - mx), e1 = __expf(v1 - mx), e2 = __expf(v2 - mx);
          float e3 = has3 ? __expf(v3 - mx) : 0.0f;
          float s = e0 + e1 + e2 + e3;
          #pragma unroll
          for (int d = 32; d >= 1; d >>= 1) s += __shfl_xor(s, d);
          float inv = 1.0f / s;
          a0 += e0 * inv; a1 += e1 * inv; a2 += e2 * inv; a3 += e3 * inv;
        }
      }
    };

    for (int mt = 0; mt < NMT; ++mt) {
      int trow = mt * 16 + c16; if (trow > T_N - 1) trow = T_N - 1;
      const int sw = (trow & 12) << 2;
      f32x4 c[4];
      #pragma unroll
      for (int i = 0; i < 4; ++i) { f32x4 z = {0.f, 0.f, 0.f, 0.f}; c[i] = z; }
      #pragma unroll
      for (int h = 0; h < 2; ++h) {
        u32x4 rm = *(const u32x4*)((const char*)ub1 + ((trow * 32 + 16 * h) ^ sw));
        #pragma unroll
        for (int kk = 0; kk < 4; ++kk) {
          long a = lut[(rm[kk] >> shq) & 0xFFu];   // LDS LUT expansion
          int ks = 4 * h + kk;
          #pragma unroll
          for (int i = 0; i < 4; ++i)
            c[i] = __builtin_amdgcn_mfma_f32_16x16x32_fp8_fp8(a, wo[i][ks], c[i], 0, 0, 0);
        }
      }
      // softmax(mt-1) only exists for mt-1 >= 3; before that all sc traffic is
      // wave-local (store_c / moscan on own cols) -> barrier elidable.
      if (mt >= 4) __syncthreads();   // prior softmax done reading sc
      store_c(c);
      moscan(mt);                     // wave-local after wave-local store
      if (mt >= 3) __syncthreads();   // membranes visible to all waves
      softmax_t(mt);
    }
    __syncthreads();

    // merge 4 per-wave accumulators via sc, store f32
    sc[wave * 260 + lane]       = a0;
    sc[wave * 260 + 64 + lane]  = a1;
    sc[wave * 260 + 128 + lane] = a2;
    if (lane < 8) sc[wave * 260 + 192 + lane] = a3;
    __syncthreads();
    if (tid < NOUT) {
      float v = sc[tid] + sc[260 + tid] + sc[520 + tid] + sc[780 + tid];
      out[(size_t)bidx * NOUT + tid] = v;
    }
  }
}

extern "C" void kernel_launch(void* const* d_in, const int* in_sizes, int n_in,
                              void* d_out, int out_size, void* d_ws, size_t ws_size,
                              hipStream_t stream) {
  (void)in_sizes; (void)n_in; (void)ws_size; (void)out_size;
  unsigned short* wsb = (unsigned short*)d_ws;
  cvt_weights<<<256, 256, 0, stream>>>(
      (const float*)d_in[1], (const float*)d_in[3], (const float*)d_in[5],
      (const float*)d_in[7], (const float*)d_in[9], wsb);
  snn_fused<<<2048, 256, 0, stream>>>(
      (const float*)d_in[0], wsb,
      (const float*)d_in[2], (const float*)d_in[4],
      (const float*)d_in[6], (const float*)d_in[8],
      (float*)d_out);
}

// Round 5
// 325.536 us; speedup vs baseline: 2.1297x; 1.0717x over previous
//
#include <hip/hip_runtime.h>
#include <math.h>

// SNN forward, fused. Inputs f32, output f32 [2048][200].
// R23: R21/R22 showed identical mystery HBM traffic (72/97 MB vs R18's
// 17.5/14.9) -> cause is in their SHARED diffs vs R18, not the LDS blob.
// This round minimizes the diff-set while keeping the 32 KB footprint:
//  - ubits: 160 rows x 8 dwords, XOR-swizzled ((row&12)<<2). NO zero-init,
//    NO read clamp needed: scan_tile's t<T_N guard stores keep=0 for rows
//    150..159 (mt=9), so every row read is previously written. Reads/writes
//    are exactly R18's pattern modulo stride.
//  - output loop: R18's unconditional 2 barriers/tile restored (no elision).
//  - layer 1 reads x direct from global (block slice 12 KB, L2-resident);
//    only remaining clamp is the global-x row (avoids OOB on last block).
//  - LDS: sc 20480 + ub0 5120 + ub1 5120 + lut 2048 = 32768 exactly
//    => 5 blocks/CU by LDS. launch_bounds (256,4) (no VGPR cap; R20 lesson).

#define T_N 150
#define DIN 20
#define H 256
#define NOUT 200
#define NMT 10
#define CST 20             // sc col stride (f32): 16 rows + 4 pad

// d_ws layout: [0,5120) shorts = bf16 W1; then fp8 bytes W2,W3,W4,Wo
#define N_W1 5120
#define F8_W2 0
#define F8_W3 65536
#define F8_W4 131072
#define F8_WO 196608
#define F8_TOT 247808

typedef short s16x8 __attribute__((ext_vector_type(8)));
typedef float f32x4 __attribute__((ext_vector_type(4)));
typedef unsigned int u32x4 __attribute__((ext_vector_type(4)));

__device__ __forceinline__ unsigned short f2bf(float f) {
  union { float f; unsigned int i; } v; v.f = f;
  unsigned int r = v.i + 0x7FFFu + ((v.i >> 16) & 1u);
  return (unsigned short)(r >> 16);
}

// f32 -> OCP e4m3 (RNE, handles subnormals; inputs |f| <= 0.25, no sat needed)
__device__ __forceinline__ unsigned char f2e4m3(float f) {
  union { float f; unsigned u; } v; v.f = f;
  unsigned s = (v.u >> 24) & 0x80u;
  unsigned mag = v.u & 0x7FFFFFFFu;
  if (mag == 0) return (unsigned char)s;
  int e = (int)(mag >> 23) - 127;
  unsigned man = mag & 0x7FFFFFu;
  unsigned q;
  if (e >= -6) {
    unsigned r = man + 0x7FFFFu + ((man >> 20) & 1u);
    if (r >= 0x800000u) { e += 1; r -= 0x800000u; }
    q = ((unsigned)(e + 7) << 3) | (r >> 20);
  } else {
    unsigned mant = 0x800000u | man;
    int sh = 14 - e;
    if (sh > 31) q = 0;
    else {
      unsigned fl = mant >> sh;
      unsigned rem = mant & ((1u << sh) - 1u);
      unsigned half = 1u << (sh - 1);
      q = fl + ((rem > half || (rem == half && (fl & 1))) ? 1u : 0u);
    }
  }
  return (unsigned char)(s | q);
}

__global__ void cvt_weights(const float* __restrict__ W1, const float* __restrict__ W2,
                            const float* __restrict__ W3, const float* __restrict__ W4,
                            const float* __restrict__ Wo, unsigned short* __restrict__ ws) {
  int idx = blockIdx.x * blockDim.x + threadIdx.x;
  int stride = gridDim.x * blockDim.x;
  for (int i = idx; i < N_W1; i += stride) ws[i] = f2bf(W1[i]);
  unsigned char* f8 = (unsigned char*)(ws + N_W1);
  for (int i = idx; i < F8_TOT; i += stride) {
    float v;
    if (i < F8_W3)      v = W2[i - F8_W2];
    else if (i < F8_W4) v = W3[i - F8_W3];
    else if (i < F8_WO) v = W4[i - F8_W4];
    else                v = Wo[i - F8_WO];
    f8[i] = f2e4m3(v);
  }
}

// expand 8 spike bits -> 8 fp8 e4m3 bytes (0x00 / 0x38) packed in a long
// (used only to BUILD the LDS LUT).
__device__ __forceinline__ long expand8_f8(unsigned t) {
  unsigned lo = ((t & 0xFu) * 0x204081u) & 0x01010101u;
  unsigned hi = ((t >> 4) * 0x204081u) & 0x01010101u;
  lo *= 0x38u; hi *= 0x38u;
  union { unsigned u[2]; long l; } cv; cv.u[0] = lo; cv.u[1] = hi;
  return cv.l;
}

__global__ __launch_bounds__(256, 4) void snn_fused(
    const float* __restrict__ x,             // [2048][150][20] f32
    const unsigned short* __restrict__ wsb,  // d_ws: bf16 W1 + fp8 W2..Wo
    const float* __restrict__ b1,            // [256] f32
    const float* __restrict__ b2,
    const float* __restrict__ b3,
    const float* __restrict__ b4,
    float* __restrict__ out)                 // [2048][200] f32
{
  __shared__ float sc[5120];               // 20480 B: col-major C scratch
  __shared__ unsigned int ub0[1280];       //  5120 B: spike bits, 160 rows swz
  __shared__ unsigned int ub1[1280];       //  5120 B
  __shared__ long lut[256];                //  2048 B: byte -> 8 fp8 spikes
                                           // total 32768 B exactly -> 5 blk/CU

  const int tid  = threadIdx.x;
  const int lane = tid & 63;
  const int wave = tid >> 6;    // 0..3
  const int c16  = lane & 15;
  const int quad = lane >> 4;
  const int shq  = quad * 8;
  const int shq2 = (quad == 3) ? 16 : shq;  // quad3 re-reads quad2's slice (its weights are 0)
  const int bidx = blockIdx.x;
  const int colw = 64 * wave;   // wave owns cols [64w, 64w+64)
  const int cb   = colw + c16;

  const unsigned char* f8 = (const unsigned char*)(wsb + N_W1);

  auto store_c = [&](f32x4* c) {
    #pragma unroll
    for (int i = 0; i < 4; ++i)
      *(f32x4*)&sc[(cb + 16 * i) * CST + quad * 4] = c[i];
  };

  // fused membrane scan, two-half form; 64 lanes own the wave's 64 cols.
  // Rows t>=150 (mt=9, lanes 6..15) store keep=0 -> no zero-init needed.
  auto scan_tile = [&](int mt, float& m, unsigned int* wb) {
    const f32x4* vp = (const f32x4*)&sc[(colw + lane) * CST];
    unsigned long long keep = 0ull;
    #pragma unroll
    for (int h = 0; h < 2; ++h) {
      f32x4 v0 = vp[2 * h], v1 = vp[2 * h + 1];
      #pragma unroll
      for (int rr = 0; rr < 8; ++rr) {
        int r = 8 * h + rr;
        int t = mt * 16 + r;
        if (t < T_N) {  // block-uniform
          float inp = (rr < 4) ? v0[rr & 3] : v1[rr & 3];
          float sel = (m > 1.0f) ? (inp - 1.0f) : inp;
          m = 0.9f * m + sel;
          unsigned long long msk = __ballot(m > 1.0f);
          if (lane == r) keep = msk;
        }
      }
    }
    int row = mt * 16 + lane;
    if (lane < 16)
      *(unsigned long long*)((char*)wb + ((row * 32 + 8 * wave) ^ ((row & 12) << 2))) = keep;
  };

  lut[tid] = expand8_f8((unsigned)tid);  // visible after post-layer-1 barrier

  // ---- layer 1 (bf16): x @ W1^T (K=20 pad 32) -> ub0; barrier-free ----
  // A-fragments straight from global x (block slice 12 KB, L1/L2-resident).
  {
    s16x8 w1f[4];
    #pragma unroll
    for (int i = 0; i < 4; ++i) {
      int n = cb + 16 * i;
      #pragma unroll
      for (int j = 0; j < 8; ++j) {
        int k = shq + j;
        w1f[i][j] = (k < DIN) ? (short)wsb[n * DIN + k] : (short)0;
      }
      asm volatile("" : "+v"(w1f[i]));
    }
    float bc[4];
    #pragma unroll
    for (int i = 0; i < 4; ++i) bc[i] = b1[cb + 16 * i];
    const float* xrow = x + (size_t)bidx * (T_N * DIN);
    float m = 0.0f;
    for (int mt = 0; mt < NMT; ++mt) {
      int tr = mt * 16 + c16; if (tr > T_N - 1) tr = T_N - 1;  // global-x OOB guard only
      const float* p = xrow + tr * DIN + shq2;   // 16B-aligned (80B rows, shq2 in {0,8,16})
      f32x4 v0 = *(const f32x4*)p;
      f32x4 v1 = {0.f, 0.f, 0.f, 0.f};
      if (shq2 < 16) v1 = *(const f32x4*)(p + 4);  // quads 0,1 only (k<16)
      s16x8 a1;
      #pragma unroll
      for (int j = 0; j < 4; ++j) {
        a1[j]     = (short)f2bf(v0[j]);
        a1[4 + j] = (short)f2bf(v1[j]);   // k=20..23 -> 0 (weights there are 0)
      }
      f32x4 c[4];
      #pragma unroll
      for (int i = 0; i < 4; ++i) { f32x4 z = {bc[i], bc[i], bc[i], bc[i]}; c[i] = z; }
      #pragma unroll
      for (int i = 0; i < 4; ++i)
        c[i] = __builtin_amdgcn_mfma_f32_16x16x32_bf16(a1, w1f[i], c[i], 0, 0, 0);
      if (mt > 0) scan_tile(mt - 1, m, ub0);
      store_c(c);
    }
    scan_tile(9, m, ub0);
  }
  __syncthreads();  // bits0 complete (incl. zero rows 150..159); lut visible

  // ---- layers 2..4 (fp8 weights): barrier-free, bits ping-pong ----
  const float* bsl[3] = {b2, b3, b4};
  const int wofs[3] = {F8_W2, F8_W3, F8_W4};
  for (int l = 0; l < 3; ++l) {
    const unsigned char* wl = f8 + wofs[l];
    unsigned int* const ubr = (l & 1) ? ub1 : ub0;
    unsigned int* const ubw = (l & 1) ? ub0 : ub1;
    __builtin_amdgcn_sched_barrier(0);
    long wf[4][8];
    #pragma unroll
    for (int i = 0; i < 4; ++i) {
      int n = cb + 16 * i;
      #pragma unroll
      for (int ks = 0; ks < 8; ++ks) {
        wf[i][ks] = *(const long*)(wl + n * H + ks * 32 + shq);
        asm volatile("" : "+v"(wf[i][ks]));
      }
    }
    __builtin_amdgcn_sched_barrier(0);
    float bc[4];
    #pragma unroll
    for (int i = 0; i < 4; ++i) bc[i] = bsl[l][cb + 16 * i];
    float m = 0.0f;
    for (int mt = 0; mt < NMT; ++mt) {
      const int trow = mt * 16 + c16;            // 0..159, always in-bounds
      const int sw = (trow & 12) << 2;
      f32x4 c[4];
      #pragma unroll
      for (int i = 0; i < 4; ++i) { f32x4 z = {bc[i], bc[i], bc[i], bc[i]}; c[i] = z; }
      #pragma unroll
      for (int h = 0; h < 2; ++h) {
        u32x4 rm = *(const u32x4*)((const char*)ubr + ((trow * 32 + 16 * h) ^ sw));
        #pragma unroll
        for (int kk = 0; kk < 4; ++kk) {
          long a = lut[(rm[kk] >> shq) & 0xFFu];   // LDS LUT expansion
          int ks = 4 * h + kk;
          #pragma unroll
          for (int i = 0; i < 4; ++i)
            c[i] = __builtin_amdgcn_mfma_f32_16x16x32_fp8_fp8(a, wf[i][ks], c[i], 0, 0, 0);
        }
      }
      if (mt > 0) scan_tile(mt - 1, m, ubw);
      store_c(c);
    }
    scan_tile(9, m, ubw);
    __syncthreads();  // bits[ubw] complete
  }

  // ---- output layer (fp8, reads ub1): GEMM + mo-scan + softmax ----
  {
    __builtin_amdgcn_sched_barrier(0);
    long wo[4][8];
    #pragma unroll
    for (int i = 0; i < 4; ++i) {
      int n = cb + 16 * i;
      bool valid = (n < NOUT);
      #pragma unroll
      for (int ks = 0; ks < 8; ++ks) {
        wo[i][ks] = valid ? *(const long*)(f8 + F8_WO + n * H + ks * 32 + shq) : 0L;
        asm volatile("" : "+v"(wo[i][ks]));
      }
    }
    __builtin_amdgcn_sched_barrier(0);

    float mo = 0.0f;
    float a0 = 0.f, a1 = 0.f, a2 = 0.f, a3 = 0.f;

    auto moscan = [&](int mt) {
      if (tid < 208) {   // wave-local: thread tid scans col tid
        f32x4* vp = (f32x4*)&sc[tid * CST];
        #pragma unroll
        for (int h = 0; h < 2; ++h) {
          f32x4 v0 = vp[2 * h], v1 = vp[2 * h + 1];
          #pragma unroll
          for (int rr = 0; rr < 8; ++rr) {
            int r = 8 * h + rr;
            int t = mt * 16 + r;
            if (t < T_N) {
              float inp = (rr < 4) ? v0[rr & 3] : v1[rr & 3];
              float reset = (mo > 1.0f) ? 1.0f : 0.0f;
              mo = 0.9f * mo + inp - reset;
              if (rr < 4) v0[rr & 3] = mo; else v1[rr & 3] = mo;
            }
          }
          vp[2 * h] = v0; vp[2 * h + 1] = v1;
        }
      }
    };
    auto softmax_t = [&](int mt) {
      #pragma unroll
      for (int rr = 0; rr < 4; ++rr) {
        int r = 4 * wave + rr;
        int t = mt * 16 + r;
        if (t > 50 && t < T_N) {        // wave-uniform
          const float* p = &sc[r];
          float v0 = p[lane * CST];
          float v1 = p[(64 + lane) * CST];
          float v2 = p[(128 + lane) * CST];
          bool has3 = (lane < 8);
          float v3 = has3 ? p[(192 + lane) * CST] : -INFINITY;
          float mx = fmaxf(fmaxf(v0, v1), fmaxf(v2, v3));
          #pragma unroll
          for (int d = 32; d >= 1; d >>= 1) mx = fmaxf(mx, __shfl_xor(mx, d));
          float e0 = __expf(v0 - mx), e1 = __expf(v1 - mx), e2 = __expf(v2 - mx);
          float e3 = has3 ? __expf(v3 - mx) : 0.0f;
          float s = e0 + e1 + e2 + e3;
          #pragma unroll
          for (int d = 32; d >= 1; d >>= 1) s += __shfl_xor(s, d);
          float inv = 1.0f / s;
          a0 += e0 * inv; a1 += e1 * inv; a2 += e2 * inv; a3 += e3 * inv;
        }
      }
    };

    for (int mt = 0; mt < NMT; ++mt) {
      const int trow = mt * 16 + c16;            // 0..159, always in-bounds
      const int sw = (trow & 12) << 2;
      f32x4 c[4];
      #pragma unroll
      for (int i = 0; i < 4; ++i) { f32x4 z = {0.f, 0.f, 0.f, 0.f}; c[i] = z; }
      #pragma unroll
      for (int h = 0; h < 2; ++h) {
        u32x4 rm = *(const u32x4*)((const char*)ub1 + ((trow * 32 + 16 * h) ^ sw));
        #pragma unroll
        for (int kk = 0; kk < 4; ++kk) {
          long a = lut[(rm[kk] >> shq) & 0xFFu];   // LDS LUT expansion
          int ks = 4 * h + kk;
          #pragma unroll
          for (int i = 0; i < 4; ++i)
            c[i] = __builtin_amdgcn_mfma_f32_16x16x32_fp8_fp8(a, wo[i][ks], c[i], 0, 0, 0);
        }
      }
      __syncthreads();              // prior softmax done reading sc (R18 pattern)
      store_c(c);
      moscan(mt);                   // wave-local after wave-local store
      __syncthreads();              // membranes visible to all waves
      softmax_t(mt);
    }
    __syncthreads();

    // merge 4 per-wave accumulators via sc, store f32
    sc[wave * 260 + lane]       = a0;
    sc[wave * 260 + 64 + lane]  = a1;
    sc[wave * 260 + 128 + lane] = a2;
    if (lane < 8) sc[wave * 260 + 192 + lane] = a3;
    __syncthreads();
    if (tid < NOUT) {
      float v = sc[tid] + sc[260 + tid] + sc[520 + tid] + sc[780 + tid];
      out[(size_t)bidx * NOUT + tid] = v;
    }
  }
}

extern "C" void kernel_launch(void* const* d_in, const int* in_sizes, int n_in,
                              void* d_out, int out_size, void* d_ws, size_t ws_size,
                              hipStream_t stream) {
  (void)in_sizes; (void)n_in; (void)ws_size; (void)out_size;
  unsigned short* wsb = (unsigned short*)d_ws;
  cvt_weights<<<256, 256, 0, stream>>>(
      (const float*)d_in[1], (const float*)d_in[3], (const float*)d_in[5],
      (const float*)d_in[7], (const float*)d_in[9], wsb);
  snn_fused<<<2048, 256, 0, stream>>>(
      (const float*)d_in[0], wsb,
      (const float*)d_in[2], (const float*)d_in[4],
      (const float*)d_in[6], (const float*)d_in[8],
      (float*)d_out);
}

// Round 6
// 310.915 us; speedup vs baseline: 2.2298x; 1.0470x over previous
//
#include <hip/hip_runtime.h>
#include <math.h>

// SNN forward, fused. Inputs f32, output f32 [2048][200].
// R24: kill ALL scratch sources, keep 32 KB LDS, R18-style typed addressing.
//  - Diagnosis: R21-R23's mystery HBM WRITE (86-97 MB vs R18 14.9) tracks
//    scratch stores; R18's own 14.9 MB matches its bsl[3]/wofs[3]
//    runtime-indexed stack arrays (~36 B/thread). Scratch backing also caps
//    resident waves -> why 5 blocks/CU never engaged.
//  - ubits: 160 rows x 8 dwords, PLAIN dword indexing (no char casts, no XOR
//    swizzle, no clamps). Rows 150-159 get zero stores from scan_tile's
//    t<T_N guard before any read. 4-way bank conflict on ~100 b128 reads/wave
//    is noise vs the existing 1e7 conflict cycles.
//  - fp8 layer loop instantiated 3x via inlined lambda with pointer params
//    (no runtime-indexed arrays anywhere in the kernel).
//  - layer 1 reads x direct from global (12 KB/block slice, L2-resident),
//    row clamp only for the global OOB guard.
//  - output loop: R18's unconditional 2 barriers/tile.
//  - LDS: sc 20480 + ub0 5120 + ub1 5120 + lut 2048 = 32768 exactly.
//  - launch_bounds (256,4): no VGPR cap (R20 lesson: (256,5) spills).

#define T_N 150
#define DIN 20
#define H 256
#define NOUT 200
#define NMT 10
#define CST 20             // sc col stride (f32): 16 rows + 4 pad

// d_ws layout: [0,5120) shorts = bf16 W1; then fp8 bytes W2,W3,W4,Wo
#define N_W1 5120
#define F8_W2 0
#define F8_W3 65536
#define F8_W4 131072
#define F8_WO 196608
#define F8_TOT 247808

typedef short s16x8 __attribute__((ext_vector_type(8)));
typedef float f32x4 __attribute__((ext_vector_type(4)));
typedef unsigned int u32x4 __attribute__((ext_vector_type(4)));

__device__ __forceinline__ unsigned short f2bf(float f) {
  union { float f; unsigned int i; } v; v.f = f;
  unsigned int r = v.i + 0x7FFFu + ((v.i >> 16) & 1u);
  return (unsigned short)(r >> 16);
}

// f32 -> OCP e4m3 (RNE, handles subnormals; inputs |f| <= 0.25, no sat needed)
__device__ __forceinline__ unsigned char f2e4m3(float f) {
  union { float f; unsigned u; } v; v.f = f;
  unsigned s = (v.u >> 24) & 0x80u;
  unsigned mag = v.u & 0x7FFFFFFFu;
  if (mag == 0) return (unsigned char)s;
  int e = (int)(mag >> 23) - 127;
  unsigned man = mag & 0x7FFFFFu;
  unsigned q;
  if (e >= -6) {
    unsigned r = man + 0x7FFFFu + ((man >> 20) & 1u);
    if (r >= 0x800000u) { e += 1; r -= 0x800000u; }
    q = ((unsigned)(e + 7) << 3) | (r >> 20);
  } else {
    unsigned mant = 0x800000u | man;
    int sh = 14 - e;
    if (sh > 31) q = 0;
    else {
      unsigned fl = mant >> sh;
      unsigned rem = mant & ((1u << sh) - 1u);
      unsigned half = 1u << (sh - 1);
      q = fl + ((rem > half || (rem == half && (fl & 1))) ? 1u : 0u);
    }
  }
  return (unsigned char)(s | q);
}

__global__ void cvt_weights(const float* __restrict__ W1, const float* __restrict__ W2,
                            const float* __restrict__ W3, const float* __restrict__ W4,
                            const float* __restrict__ Wo, unsigned short* __restrict__ ws) {
  int idx = blockIdx.x * blockDim.x + threadIdx.x;
  int stride = gridDim.x * blockDim.x;
  for (int i = idx; i < N_W1; i += stride) ws[i] = f2bf(W1[i]);
  unsigned char* f8 = (unsigned char*)(ws + N_W1);
  for (int i = idx; i < F8_TOT; i += stride) {
    float v;
    if (i < F8_W3)      v = W2[i - F8_W2];
    else if (i < F8_W4) v = W3[i - F8_W3];
    else if (i < F8_WO) v = W4[i - F8_W4];
    else                v = Wo[i - F8_WO];
    f8[i] = f2e4m3(v);
  }
}

// expand 8 spike bits -> 8 fp8 e4m3 bytes (0x00 / 0x38) packed in a long
// (used only to BUILD the LDS LUT).
__device__ __forceinline__ long expand8_f8(unsigned t) {
  unsigned lo = ((t & 0xFu) * 0x204081u) & 0x01010101u;
  unsigned hi = ((t >> 4) * 0x204081u) & 0x01010101u;
  lo *= 0x38u; hi *= 0x38u;
  union { unsigned u[2]; long l; } cv; cv.u[0] = lo; cv.u[1] = hi;
  return cv.l;
}

__global__ __launch_bounds__(256, 4) void snn_fused(
    const float* __restrict__ x,             // [2048][150][20] f32
    const unsigned short* __restrict__ wsb,  // d_ws: bf16 W1 + fp8 W2..Wo
    const float* __restrict__ b1,            // [256] f32
    const float* __restrict__ b2,
    const float* __restrict__ b3,
    const float* __restrict__ b4,
    float* __restrict__ out)                 // [2048][200] f32
{
  __shared__ float sc[5120];               // 20480 B: col-major C scratch
  __shared__ unsigned int ub0[1280];       //  5120 B: spike bits, 160 rows x 8 dw
  __shared__ unsigned int ub1[1280];       //  5120 B
  __shared__ long lut[256];                //  2048 B: byte -> 8 fp8 spikes
                                           // total 32768 B exactly

  const int tid  = threadIdx.x;
  const int lane = tid & 63;
  const int wave = tid >> 6;    // 0..3
  const int c16  = lane & 15;
  const int quad = lane >> 4;
  const int shq  = quad * 8;
  const int shq2 = (quad == 3) ? 16 : shq;  // quad3 re-reads quad2's slice (its weights are 0)
  const int bidx = blockIdx.x;
  const int colw = 64 * wave;   // wave owns cols [64w, 64w+64)
  const int cb   = colw + c16;

  const unsigned char* f8 = (const unsigned char*)(wsb + N_W1);

  auto store_c = [&](f32x4* c) {
    #pragma unroll
    for (int i = 0; i < 4; ++i)
      *(f32x4*)&sc[(cb + 16 * i) * CST + quad * 4] = c[i];
  };

  // fused membrane scan, two-half form; 64 lanes own the wave's 64 cols.
  // Rows t>=150 (mt=9, lanes 6..15) store keep=0 -> no zero-init needed.
  auto scan_tile = [&](int mt, float& m, unsigned int* wb) {
    const f32x4* vp = (const f32x4*)&sc[(colw + lane) * CST];
    unsigned long long keep = 0ull;
    #pragma unroll
    for (int h = 0; h < 2; ++h) {
      f32x4 v0 = vp[2 * h], v1 = vp[2 * h + 1];
      #pragma unroll
      for (int rr = 0; rr < 8; ++rr) {
        int r = 8 * h + rr;
        int t = mt * 16 + r;
        if (t < T_N) {  // block-uniform
          float inp = (rr < 4) ? v0[rr & 3] : v1[rr & 3];
          float sel = (m > 1.0f) ? (inp - 1.0f) : inp;
          m = 0.9f * m + sel;
          unsigned long long msk = __ballot(m > 1.0f);
          if (lane == r) keep = msk;
        }
      }
    }
    int row = mt * 16 + lane;
    if (lane < 16)
      *(unsigned long long*)&wb[row * 8 + 2 * wave] = keep;
  };

  lut[tid] = expand8_f8((unsigned)tid);  // visible after post-layer-1 barrier

  // ---- layer 1 (bf16): x @ W1^T (K=20 pad 32) -> ub0; barrier-free ----
  // A-fragments straight from global x (block slice 12 KB, L1/L2-resident).
  {
    s16x8 w1f[4];
    #pragma unroll
    for (int i = 0; i < 4; ++i) {
      int n = cb + 16 * i;
      #pragma unroll
      for (int j = 0; j < 8; ++j) {
        int k = shq + j;
        w1f[i][j] = (k < DIN) ? (short)wsb[n * DIN + k] : (short)0;
      }
      asm volatile("" : "+v"(w1f[i]));
    }
    float bc[4];
    #pragma unroll
    for (int i = 0; i < 4; ++i) bc[i] = b1[cb + 16 * i];
    const float* xrow = x + (size_t)bidx * (T_N * DIN);
    float m = 0.0f;
    for (int mt = 0; mt < NMT; ++mt) {
      int tr = mt * 16 + c16; if (tr > T_N - 1) tr = T_N - 1;  // global-x OOB guard only
      const float* p = xrow + tr * DIN + shq2;   // 16B-aligned (80B rows, shq2 in {0,8,16})
      f32x4 v0 = *(const f32x4*)p;
      f32x4 v1 = {0.f, 0.f, 0.f, 0.f};
      if (shq2 < 16) v1 = *(const f32x4*)(p + 4);  // quads 0,1 only (k<16)
      s16x8 a1;
      #pragma unroll
      for (int j = 0; j < 4; ++j) {
        a1[j]     = (short)f2bf(v0[j]);
        a1[4 + j] = (short)f2bf(v1[j]);   // k=20..23 -> 0 (weights there are 0)
      }
      f32x4 c[4];
      #pragma unroll
      for (int i = 0; i < 4; ++i) { f32x4 z = {bc[i], bc[i], bc[i], bc[i]}; c[i] = z; }
      #pragma unroll
      for (int i = 0; i < 4; ++i)
        c[i] = __builtin_amdgcn_mfma_f32_16x16x32_bf16(a1, w1f[i], c[i], 0, 0, 0);
      if (mt > 0) scan_tile(mt - 1, m, ub0);
      store_c(c);
    }
    scan_tile(9, m, ub0);
  }
  __syncthreads();  // bits0 complete (incl. zero rows 150..159); lut visible

  // ---- layers 2..4 (fp8 weights): barrier-free, bits ping-pong ----
  // Instantiated 3x with constant pointers: NO runtime-indexed stack arrays.
  auto layer_f8 = [&](const unsigned char* wl, const float* __restrict__ bias,
                      const unsigned int* ubr, unsigned int* ubw) {
    __builtin_amdgcn_sched_barrier(0);
    long wf[4][8];
    #pragma unroll
    for (int i = 0; i < 4; ++i) {
      int n = cb + 16 * i;
      #pragma unroll
      for (int ks = 0; ks < 8; ++ks) {
        wf[i][ks] = *(const long*)(wl + n * H + ks * 32 + shq);
        asm volatile("" : "+v"(wf[i][ks]));
      }
    }
    __builtin_amdgcn_sched_barrier(0);
    float bc[4];
    #pragma unroll
    for (int i = 0; i < 4; ++i) bc[i] = bias[cb + 16 * i];
    float m = 0.0f;
    for (int mt = 0; mt < NMT; ++mt) {
      const int trow = mt * 16 + c16;            // 0..159, always in-bounds
      f32x4 c[4];
      #pragma unroll
      for (int i = 0; i < 4; ++i) { f32x4 z = {bc[i], bc[i], bc[i], bc[i]}; c[i] = z; }
      #pragma unroll
      for (int h = 0; h < 2; ++h) {
        u32x4 rm = *(const u32x4*)&ubr[trow * 8 + 4 * h];
        #pragma unroll
        for (int kk = 0; kk < 4; ++kk) {
          long a = lut[(rm[kk] >> shq) & 0xFFu];   // LDS LUT expansion
          int ks = 4 * h + kk;
          #pragma unroll
          for (int i = 0; i < 4; ++i)
            c[i] = __builtin_amdgcn_mfma_f32_16x16x32_fp8_fp8(a, wf[i][ks], c[i], 0, 0, 0);
        }
      }
      if (mt > 0) scan_tile(mt - 1, m, ubw);
      store_c(c);
    }
    scan_tile(9, m, ubw);
    __syncthreads();  // bits[ubw] complete
  };
  layer_f8(f8 + F8_W2, b2, ub0, ub1);
  layer_f8(f8 + F8_W3, b3, ub1, ub0);
  layer_f8(f8 + F8_W4, b4, ub0, ub1);

  // ---- output layer (fp8, reads ub1): GEMM + mo-scan + softmax ----
  {
    __builtin_amdgcn_sched_barrier(0);
    long wo[4][8];
    #pragma unroll
    for (int i = 0; i < 4; ++i) {
      int n = cb + 16 * i;
      bool valid = (n < NOUT);
      #pragma unroll
      for (int ks = 0; ks < 8; ++ks) {
        wo[i][ks] = valid ? *(const long*)(f8 + F8_WO + n * H + ks * 32 + shq) : 0L;
        asm volatile("" : "+v"(wo[i][ks]));
      }
    }
    __builtin_amdgcn_sched_barrier(0);

    float mo = 0.0f;
    float a0 = 0.f, a1 = 0.f, a2 = 0.f, a3 = 0.f;

    auto moscan = [&](int mt) {
      if (tid < 208) {   // wave-local: thread tid scans col tid
        f32x4* vp = (f32x4*)&sc[tid * CST];
        #pragma unroll
        for (int h = 0; h < 2; ++h) {
          f32x4 v0 = vp[2 * h], v1 = vp[2 * h + 1];
          #pragma unroll
          for (int rr = 0; rr < 8; ++rr) {
            int r = 8 * h + rr;
            int t = mt * 16 + r;
            if (t < T_N) {
              float inp = (rr < 4) ? v0[rr & 3] : v1[rr & 3];
              float reset = (mo > 1.0f) ? 1.0f : 0.0f;
              mo = 0.9f * mo + inp - reset;
              if (rr < 4) v0[rr & 3] = mo; else v1[rr & 3] = mo;
            }
          }
          vp[2 * h] = v0; vp[2 * h + 1] = v1;
        }
      }
    };
    auto softmax_t = [&](int mt) {
      #pragma unroll
      for (int rr = 0; rr < 4; ++rr) {
        int r = 4 * wave + rr;
        int t = mt * 16 + r;
        if (t > 50 && t < T_N) {        // wave-uniform
          const float* p = &sc[r];
          float v0 = p[lane * CST];
          float v1 = p[(64 + lane) * CST];
          float v2 = p[(128 + lane) * CST];
          bool has3 = (lane < 8);
          float v3 = has3 ? p[(192 + lane) * CST] : -INFINITY;
          float mx = fmaxf(fmaxf(v0, v1), fmaxf(v2, v3));
          #pragma unroll
          for (int d = 32; d >= 1; d >>= 1) mx = fmaxf(mx, __shfl_xor(mx, d));
          float e0 = __expf(v0 - mx), e1 = __expf(v1 - mx), e2 = __expf(v2 - mx);
          float e3 = has3 ? __expf(v3 - mx) : 0.0f;
          float s = e0 + e1 + e2 + e3;
          #pragma unroll
          for (int d = 32; d >= 1; d >>= 1) s += __shfl_xor(s, d);
          float inv = 1.0f / s;
          a0 += e0 * inv; a1 += e1 * inv; a2 += e2 * inv; a3 += e3 * inv;
        }
      }
    };

    for (int mt = 0; mt < NMT; ++mt) {
      const int trow = mt * 16 + c16;            // 0..159, always in-bounds
      f32x4 c[4];
      #pragma unroll
      for (int i = 0; i < 4; ++i) { f32x4 z = {0.f, 0.f, 0.f, 0.f}; c[i] = z; }
      #pragma unroll
      for (int h = 0; h < 2; ++h) {
        u32x4 rm = *(const u32x4*)&ub1[trow * 8 + 4 * h];
        #pragma unroll
        for (int kk = 0; kk < 4; ++kk) {
          long a = lut[(rm[kk] >> shq) & 0xFFu];   // LDS LUT expansion
          int ks = 4 * h + kk;
          #pragma unroll
          for (int i = 0; i < 4; ++i)
            c[i] = __builtin_amdgcn_mfma_f32_16x16x32_fp8_fp8(a, wo[i][ks], c[i], 0, 0, 0);
        }
      }
      __syncthreads();              // prior softmax done reading sc (R18 pattern)
      store_c(c);
      moscan(mt);                   // wave-local after wave-local store
      __syncthreads();              // membranes visible to all waves
      softmax_t(mt);
    }
    __syncthreads();

    // merge 4 per-wave accumulators via sc, store f32
    sc[wave * 260 + lane]       = a0;
    sc[wave * 260 + 64 + lane]  = a1;
    sc[wave * 260 + 128 + lane] = a2;
    if (lane < 8) sc[wave * 260 + 192 + lane] = a3;
    __syncthreads();
    if (tid < NOUT) {
      float v = sc[tid] + sc[260 + tid] + sc[520 + tid] + sc[780 + tid];
      out[(size_t)bidx * NOUT + tid] = v;
    }
  }
}

extern "C" void kernel_launch(void* const* d_in, const int* in_sizes, int n_in,
                              void* d_out, int out_size, void* d_ws, size_t ws_size,
                              hipStream_t stream) {
  (void)in_sizes; (void)n_in; (void)ws_size; (void)out_size;
  unsigned short* wsb = (unsigned short*)d_ws;
  cvt_weights<<<256, 256, 0, stream>>>(
      (const float*)d_in[1], (const float*)d_in[3], (const float*)d_in[5],
      (const float*)d_in[7], (const float*)d_in[9], wsb);
  snn_fused<<<2048, 256, 0, stream>>>(
      (const float*)d_in[0], wsb,
      (const float*)d_in[2], (const float*)d_in[4],
      (const float*)d_in[6], (const float*)d_in[8],
      (float*)d_out);
}